// Round 2
// baseline (132.975 us; speedup 1.0000x reference)
//
#include <hip/hip_runtime.h>
#include <cstdint>

#define NQ    8192
#define NNEG  16384
#define DIM   128
#define SPLIT 16
#define CHUNK (NNEG / SPLIT)          // 1024
// (1/TAU) * log2(e): MFMA output is directly the base-2 exponent
#define K_SCALE 7.2134752044448169f
#define LN2     0.69314718055994531f

typedef __attribute__((ext_vector_type(8))) __bf16 bf16x8;
typedef __attribute__((ext_vector_type(4))) float  f32x4;

__device__ inline void async_load16(const void* g, void* l) {
    __builtin_amdgcn_global_load_lds(
        (const __attribute__((address_space(1))) void*)g,
        (__attribute__((address_space(3))) void*)l, 16, 0, 0);
}

__device__ inline unsigned short f2bf(float x) {
    uint32_t u = __float_as_uint(x);
    u += 0x7fffu + ((u >> 16) & 1u);      // round-to-nearest-even
    return (unsigned short)(u >> 16);
}

__device__ inline float waveReduceSum(float v) {
#pragma unroll
    for (int m = 32; m >= 1; m >>= 1) v += __shfl_xor(v, m, 64);
    return v;
}

// ---------------- kernel 1: convert bf16 + fused positive-logit dot ----------------
// blocks 0..1023 handle Q (and pos dot); blocks 1024..3071 handle neg.
__global__ __launch_bounds__(256) void iw_prep(
    const float* __restrict__ q, const float* __restrict__ p,
    const float* __restrict__ neg,
    unsigned short* __restrict__ qb, unsigned short* __restrict__ nb,
    float* __restrict__ out)
{
    const int tid = threadIdx.x;
    const int i = blockIdx.x * 256 + tid;
    constexpr int QG = NQ * DIM / 4;      // 262144 float4 groups of Q
    if (i < QG) {
        float4 v = ((const float4*)q)[i];
        ushort4 o;
        o.x = f2bf(v.x * K_SCALE); o.y = f2bf(v.y * K_SCALE);
        o.z = f2bf(v.z * K_SCALE); o.w = f2bf(v.w * K_SCALE);
        ((ushort4*)qb)[i] = o;
        // fused pos logit: q . pos (raw f32)
        float4 pv = ((const float4*)p)[i];
        float acc = fmaf(v.x, pv.x, fmaf(v.y, pv.y, fmaf(v.z, pv.z, v.w * pv.w)));
        acc = waveReduceSum(acc);
        __shared__ float red[4];
        if ((tid & 63) == 0) red[tid >> 6] = acc;
        __syncthreads();
        if (tid == 0) {
            float s = red[0] + red[1] + red[2] + red[3];
            atomicAdd(out, s * (-1.0f / (0.2f * (float)NQ)));
        }
    } else {
        int j = i - QG;                   // < 524288
        float4 v = ((const float4*)neg)[j];
        ushort4 o;
        o.x = f2bf(v.x); o.y = f2bf(v.y); o.z = f2bf(v.z); o.w = f2bf(v.w);
        ((ushort4*)nb)[j] = o;
    }
}

// ---------------- kernel 2: flash-LSE main ----------------
// grid (64, 16): blockIdx.x = row block (BM=128), blockIdx.y = neg chunk (1024)
__global__ __launch_bounds__(256, 4) void iw_main(
    const unsigned short* __restrict__ qb, const unsigned short* __restrict__ nb,
    float2* __restrict__ partial)
{
    constexpr int BM = 128, BN = 64, NIT = CHUNK / BN;     // 16 iters
    __shared__ alignas(16) unsigned short n_lds[2 * BN * DIM]; // 2 x 16 KB, swizzled

    const int tid  = threadIdx.x;
    const int lane = tid & 63;
    const int w    = tid >> 6;        // wave 0..3, owns 32 query rows
    const int quad = lane >> 4;
    const int c0   = lane & 15;

    const int row0   = blockIdx.x * BM;
    const int nbase0 = blockIdx.y * CHUNK;

    // ---- A fragments straight from global (one-time; reused all 16 iters) ----
    // A[m = c0][k = ks*32 + quad*8 + j]
    bf16x8 afrag[2][4];
#pragma unroll
    for (int rs = 0; rs < 2; ++rs)
#pragma unroll
        for (int ks = 0; ks < 4; ++ks) {
            const int qrow = row0 + w * 32 + rs * 16 + c0;
            afrag[rs][ks] = *reinterpret_cast<const bf16x8*>(
                qb + (size_t)qrow * DIM + ks * 32 + quad * 8);
        }

    // ---- staging offsets (iter-invariant), XOR-swizzled via SOURCE address ----
    int nro[4], ndst[4];
#pragma unroll
    for (int pp = 0; pp < 4; ++pp) {
        int t   = w * 4 + pp;
        int idx = t * 64 + lane;
        int r   = idx >> 4;
        int kb  = (idx & 15) ^ (r & 15);
        nro[pp]  = r * DIM + kb * 8;
        ndst[pp] = t * 512;
    }
    // prefetch tile 0 into buf 0
#pragma unroll
    for (int pp = 0; pp < 4; ++pp)
        async_load16(nb + (size_t)nbase0 * DIM + nro[pp], n_lds + ndst[pp]);
    __syncthreads();

    float m_s[2][4], l_s[2][4];
#pragma unroll
    for (int rs = 0; rs < 2; ++rs)
#pragma unroll
        for (int i = 0; i < 4; ++i) { m_s[rs][i] = -1e30f; l_s[rs][i] = 0.f; }

    const f32x4 zero4 = {0.f, 0.f, 0.f, 0.f};

    for (int it = 0; it < NIT; ++it) {
        const int buf  = (it & 1) * (BN * DIM);
        // issue async prefetch of tile it+1 into the other buffer
        if (it + 1 < NIT) {
            const unsigned short* src = nb + (size_t)(nbase0 + (it + 1) * BN) * DIM;
            const int nbuf = ((it + 1) & 1) * (BN * DIM);
#pragma unroll
            for (int pp = 0; pp < 4; ++pp)
                async_load16(src + nro[pp], n_lds + nbuf + ndst[pp]);
        }

        f32x4 acc[2][4];
#pragma unroll
        for (int rs = 0; rs < 2; ++rs)
#pragma unroll
            for (int ns = 0; ns < 4; ++ns) acc[rs][ns] = zero4;

#pragma unroll
        for (int ns = 0; ns < 4; ++ns) {
#pragma unroll
            for (int ks = 0; ks < 4; ++ks) {
                int blk = (ns * 16 + c0) * 16 + ((ks * 4 + quad) ^ c0);
                bf16x8 b = *reinterpret_cast<const bf16x8*>(n_lds + buf + blk * 8);
                acc[0][ns] = __builtin_amdgcn_mfma_f32_16x16x32_bf16(afrag[0][ks], b, acc[0][ns], 0, 0, 0);
                acc[1][ns] = __builtin_amdgcn_mfma_f32_16x16x32_bf16(afrag[1][ks], b, acc[1][ns], 0, 0, 0);
            }
        }

        // per-lane online logsumexp update (pure VALU, overlaps prefetch drain)
#pragma unroll
        for (int rs = 0; rs < 2; ++rs) {
#pragma unroll
            for (int i = 0; i < 4; ++i) {
                float y0 = acc[rs][0][i], y1 = acc[rs][1][i];
                float y2 = acc[rs][2][i], y3 = acc[rs][3][i];
                float mx = fmaxf(fmaxf(y0, y1), fmaxf(y2, y3));
                float m0 = m_s[rs][i];
                float nm = fmaxf(m0, mx);
                float t  = __builtin_amdgcn_exp2f(y0 - nm) + __builtin_amdgcn_exp2f(y1 - nm)
                         + __builtin_amdgcn_exp2f(y2 - nm) + __builtin_amdgcn_exp2f(y3 - nm);
                l_s[rs][i] = l_s[rs][i] * __builtin_amdgcn_exp2f(m0 - nm) + t;
                m_s[rs][i] = nm;
            }
        }
        __syncthreads();   // drains this wave's prefetch; tile it+1 visible; buf free
    }

    // ---- merge (m,l) across the 16 lanes of each quad-row group ----
#pragma unroll
    for (int rs = 0; rs < 2; ++rs) {
#pragma unroll
        for (int i = 0; i < 4; ++i) {
            float m = m_s[rs][i], l = l_s[rs][i];
#pragma unroll
            for (int s = 1; s < 16; s <<= 1) {
                float om = __shfl_xor(m, s, 64);
                float ol = __shfl_xor(l, s, 64);
                float nm = fmaxf(m, om);
                l = l * __builtin_amdgcn_exp2f(m - nm) + ol * __builtin_amdgcn_exp2f(om - nm);
                m = nm;
            }
            if (c0 == 0) {
                int grow = row0 + w * 32 + rs * 16 + quad * 4 + i;
                partial[(size_t)blockIdx.y * NQ + grow] = make_float2(m, l);
            }
        }
    }
}

// ---------------- kernel 3: merge chunks + mean reduce ----------------
__global__ __launch_bounds__(256) void iw_merge(
    const float2* __restrict__ partial, float* __restrict__ out)
{
    const int tid = threadIdx.x;
    const int row = blockIdx.x * 256 + tid;   // 32 blocks * 256 = 8192
    float M = -1e30f, L = 0.f;
#pragma unroll
    for (int c = 0; c < SPLIT; ++c) {
        float2 p = partial[(size_t)c * NQ + row];
        float nm = fmaxf(M, p.x);
        L = L * __builtin_amdgcn_exp2f(M - nm) + p.y * __builtin_amdgcn_exp2f(p.x - nm);
        M = nm;
    }
    float lse = LN2 * (M + __log2f(L));       // natural-log LSE of scores/tau
    float v = lse * (1.0f / (float)NQ);
    v = waveReduceSum(v);
    __shared__ float red[4];
    if ((tid & 63) == 0) red[tid >> 6] = v;
    __syncthreads();
    if (tid == 0) atomicAdd(out, red[0] + red[1] + red[2] + red[3]);
}

// ---------------- launch ----------------
extern "C" void kernel_launch(void* const* d_in, const int* in_sizes, int n_in,
                              void* d_out, int out_size, void* d_ws, size_t ws_size,
                              hipStream_t stream) {
    const float* q   = (const float*)d_in[0];
    const float* pos = (const float*)d_in[1];
    const float* neg = (const float*)d_in[2];
    float* out = (float*)d_out;

    unsigned short* qb = (unsigned short*)d_ws;                    // 2 MB
    unsigned short* nb = qb + (size_t)NQ * DIM;                    // 4 MB
    float2* partial    = (float2*)(nb + (size_t)NNEG * DIM);       // 1 MB

    hipMemsetAsync(out, 0, sizeof(float), stream);
    iw_prep <<<3072, 256, 0, stream>>>(q, pos, neg, qb, nb, out);
    iw_main <<<dim3(NQ / 128, SPLIT), 256, 0, stream>>>(qb, nb, partial);
    iw_merge<<<32,   256, 0, stream>>>(partial, out);
}

// Round 3
// 112.602 us; speedup vs baseline: 1.1809x; 1.1809x over previous
//
#include <hip/hip_runtime.h>
#include <cstdint>

#define NQ    8192
#define NNEG  16384
#define DIM   128
#define SPLIT 16
#define CHUNK (NNEG / SPLIT)          // 1024
// (1/TAU) * log2(e): MFMA output is directly the base-2 exponent
#define K_SCALE 7.2134752044448169f
#define LN2     0.69314718055994531f

typedef __attribute__((ext_vector_type(8))) int   i32x8;
typedef __attribute__((ext_vector_type(4))) float f32x4;

union U8 { i32x8 v; int4 h[2]; };

__device__ inline void async_load16(const void* g, void* l) {
    __builtin_amdgcn_global_load_lds(
        (const __attribute__((address_space(1))) void*)g,
        (__attribute__((address_space(3))) void*)l, 16, 0, 0);
}

__device__ inline float waveReduceSum(float v) {
#pragma unroll
    for (int m = 32; m >= 1; m >>= 1) v += __shfl_xor(v, m, 64);
    return v;
}

// ---------------- kernel 1: f32 -> fp8 e4m3 convert + fused positive-logit dot ----
// Each thread handles 8 elements. Q threads also do the pos-dot.
__global__ __launch_bounds__(256) void iw_prep(
    const float* __restrict__ q, const float* __restrict__ p,
    const float* __restrict__ neg,
    unsigned char* __restrict__ qb8, unsigned char* __restrict__ nb8,
    float* __restrict__ out)
{
    const int tid = threadIdx.x;
    const int t = blockIdx.x * 256 + tid;
    constexpr int QT = NQ * DIM / 8;      // 131072 q-threads
    if (t < QT) {
        const float4* q4 = (const float4*)q;
        float4 v0 = q4[t * 2], v1 = q4[t * 2 + 1];
        int w0 = __builtin_amdgcn_cvt_pk_fp8_f32(v0.x * K_SCALE, v0.y * K_SCALE, 0, false);
        w0     = __builtin_amdgcn_cvt_pk_fp8_f32(v0.z * K_SCALE, v0.w * K_SCALE, w0, true);
        int w1 = __builtin_amdgcn_cvt_pk_fp8_f32(v1.x * K_SCALE, v1.y * K_SCALE, 0, false);
        w1     = __builtin_amdgcn_cvt_pk_fp8_f32(v1.z * K_SCALE, v1.w * K_SCALE, w1, true);
        ((int2*)qb8)[t] = make_int2(w0, w1);
        // fused pos logit: q . pos (raw f32)
        const float4* p4 = (const float4*)p;
        float4 p0 = p4[t * 2], p1 = p4[t * 2 + 1];
        float acc = fmaf(v0.x, p0.x, fmaf(v0.y, p0.y, fmaf(v0.z, p0.z, v0.w * p0.w)));
        acc = fmaf(v1.x, p1.x, fmaf(v1.y, p1.y, fmaf(v1.z, p1.z, fmaf(v1.w, p1.w, acc))));
        acc = waveReduceSum(acc);
        __shared__ float red[4];
        if ((tid & 63) == 0) red[tid >> 6] = acc;
        __syncthreads();
        if (tid == 0) {
            float s = red[0] + red[1] + red[2] + red[3];
            atomicAdd(out, s * (-1.0f / (0.2f * (float)NQ)));
        }
    } else {
        int j = t - QT;                   // < 262144
        const float4* n4 = (const float4*)neg;
        float4 v0 = n4[j * 2], v1 = n4[j * 2 + 1];
        int w0 = __builtin_amdgcn_cvt_pk_fp8_f32(v0.x, v0.y, 0, false);
        w0     = __builtin_amdgcn_cvt_pk_fp8_f32(v0.z, v0.w, w0, true);
        int w1 = __builtin_amdgcn_cvt_pk_fp8_f32(v1.x, v1.y, 0, false);
        w1     = __builtin_amdgcn_cvt_pk_fp8_f32(v1.z, v1.w, w1, true);
        ((int2*)nb8)[j] = make_int2(w0, w1);
    }
}

// ---------------- kernel 2: flash-LSE main (MX-fp8, K=128/instr) ----------------
// grid (64, 16): blockIdx.x = row block (BM=128), blockIdx.y = neg chunk (1024)
__global__ __launch_bounds__(256, 4) void iw_main(
    const unsigned char* __restrict__ qb8, const unsigned char* __restrict__ nb8,
    float2* __restrict__ partial)
{
    constexpr int BM = 128, BN = 64, NIT = CHUNK / BN;        // 16 iters
    __shared__ alignas(16) unsigned char n_lds[2 * BN * DIM]; // 2 x 8 KB

    const int tid  = threadIdx.x;
    const int lane = tid & 63;
    const int w    = tid >> 6;        // wave 0..3, owns 32 query rows
    const int quad = lane >> 4;
    const int c0   = lane & 15;

    const int row0   = blockIdx.x * BM;
    const int nbase0 = blockIdx.y * CHUNK;

    // ---- A fragments straight from global (fp8 row-major; 32 B/lane = K slice) ----
    U8 afrag[2];
#pragma unroll
    for (int rs = 0; rs < 2; ++rs) {
        const int qrow = row0 + w * 32 + rs * 16 + c0;
        const int4* pa = reinterpret_cast<const int4*>(qb8 + (size_t)qrow * DIM + quad * 32);
        afrag[rs].h[0] = pa[0];
        afrag[rs].h[1] = pa[1];
    }

    // ---- staging offsets: granule (r, kbx) in LDS holds global chunk kbx^(r&3) ----
    int srcoff[2], dstoff[2];
#pragma unroll
    for (int j = 0; j < 2; ++j) {
        int L  = (w * 2 + j) * 64 + lane;   // 0..511
        int h  = L & 1, G = L >> 1;
        int r  = G >> 2;
        int kb = (G & 3) ^ (r & 3);
        srcoff[j] = r * DIM + kb * 32 + h * 16;
        dstoff[j] = (w * 2 + j) * 1024;     // wave-uniform dest base (+lane*16 by HW)
    }
    // prefetch tile 0 into buf 0
#pragma unroll
    for (int j = 0; j < 2; ++j)
        async_load16(nb8 + (size_t)nbase0 * DIM + srcoff[j], n_lds + dstoff[j]);
    __syncthreads();

    float m_s[2][4], l_s[2][4];
#pragma unroll
    for (int rs = 0; rs < 2; ++rs)
#pragma unroll
        for (int i = 0; i < 4; ++i) { m_s[rs][i] = -1e30f; l_s[rs][i] = 0.f; }

    const f32x4 zero4 = {0.f, 0.f, 0.f, 0.f};

    for (int it = 0; it < NIT; ++it) {
        const int buf = (it & 1) * (BN * DIM);
        if (it + 1 < NIT) {   // async prefetch next tile into the other buffer
            const unsigned char* src = nb8 + (size_t)(nbase0 + (it + 1) * BN) * DIM;
            const int nbuf = ((it + 1) & 1) * (BN * DIM);
#pragma unroll
            for (int j = 0; j < 2; ++j)
                async_load16(src + srcoff[j], n_lds + nbuf + dstoff[j]);
        }

        f32x4 acc[2][4];
#pragma unroll
        for (int ns = 0; ns < 4; ++ns) {
            int c  = ns * 16 + c0;
            int g0 = (c << 2) + (quad ^ (c & 3));
            const int4* pb = reinterpret_cast<const int4*>(n_lds + buf + g0 * 32);
            U8 b;
            b.h[0] = pb[0];
            b.h[1] = pb[1];
            acc[0][ns] = __builtin_amdgcn_mfma_scale_f32_16x16x128_f8f6f4(
                afrag[0].v, b.v, zero4, 0, 0, 0, 127, 0, 127);
            acc[1][ns] = __builtin_amdgcn_mfma_scale_f32_16x16x128_f8f6f4(
                afrag[1].v, b.v, zero4, 0, 0, 0, 127, 0, 127);
        }

        // per-lane online logsumexp update (pure VALU, overlaps prefetch drain)
#pragma unroll
        for (int rs = 0; rs < 2; ++rs) {
#pragma unroll
            for (int i = 0; i < 4; ++i) {
                float y0 = acc[rs][0][i], y1 = acc[rs][1][i];
                float y2 = acc[rs][2][i], y3 = acc[rs][3][i];
                float mx = fmaxf(fmaxf(y0, y1), fmaxf(y2, y3));
                float m0 = m_s[rs][i];
                float nm = fmaxf(m0, mx);
                float t  = __builtin_amdgcn_exp2f(y0 - nm) + __builtin_amdgcn_exp2f(y1 - nm)
                         + __builtin_amdgcn_exp2f(y2 - nm) + __builtin_amdgcn_exp2f(y3 - nm);
                l_s[rs][i] = l_s[rs][i] * __builtin_amdgcn_exp2f(m0 - nm) + t;
                m_s[rs][i] = nm;
            }
        }
        __syncthreads();   // drains prefetch (vmcnt) + all ds_reads; buffer swap safe
    }

    // ---- merge (m,l) across the 16 lanes of each quad-row group ----
#pragma unroll
    for (int rs = 0; rs < 2; ++rs) {
#pragma unroll
        for (int i = 0; i < 4; ++i) {
            float m = m_s[rs][i], l = l_s[rs][i];
#pragma unroll
            for (int s = 1; s < 16; s <<= 1) {
                float om = __shfl_xor(m, s, 64);
                float ol = __shfl_xor(l, s, 64);
                float nm = fmaxf(m, om);
                l = l * __builtin_amdgcn_exp2f(m - nm) + ol * __builtin_amdgcn_exp2f(om - nm);
                m = nm;
            }
            if (c0 == 0) {
                int grow = row0 + w * 32 + rs * 16 + quad * 4 + i;
                partial[(size_t)blockIdx.y * NQ + grow] = make_float2(m, l);
            }
        }
    }
}

// ---------------- kernel 3: merge chunks + mean reduce ----------------
__global__ __launch_bounds__(256) void iw_merge(
    const float2* __restrict__ partial, float* __restrict__ out)
{
    const int tid = threadIdx.x;
    const int row = blockIdx.x * 256 + tid;   // 32 blocks * 256 = 8192
    float M = -1e30f, L = 0.f;
#pragma unroll
    for (int c = 0; c < SPLIT; ++c) {
        float2 p = partial[(size_t)c * NQ + row];
        float nm = fmaxf(M, p.x);
        L = L * __builtin_amdgcn_exp2f(M - nm) + p.y * __builtin_amdgcn_exp2f(p.x - nm);
        M = nm;
    }
    float lse = LN2 * (M + __log2f(L));       // natural-log LSE of scores/tau
    float v = lse * (1.0f / (float)NQ);
    v = waveReduceSum(v);
    __shared__ float red[4];
    if ((tid & 63) == 0) red[tid >> 6] = v;
    __syncthreads();
    if (tid == 0) atomicAdd(out, red[0] + red[1] + red[2] + red[3]);
}

// ---------------- launch ----------------
extern "C" void kernel_launch(void* const* d_in, const int* in_sizes, int n_in,
                              void* d_out, int out_size, void* d_ws, size_t ws_size,
                              hipStream_t stream) {
    const float* q   = (const float*)d_in[0];
    const float* pos = (const float*)d_in[1];
    const float* neg = (const float*)d_in[2];
    float* out = (float*)d_out;

    unsigned char* qb8 = (unsigned char*)d_ws;                     // 1 MB
    unsigned char* nb8 = qb8 + (size_t)NQ * DIM;                   // 2 MB
    float2* partial    = (float2*)(nb8 + (size_t)NNEG * DIM);      // 1 MB

    hipMemsetAsync(out, 0, sizeof(float), stream);
    iw_prep <<<1536, 256, 0, stream>>>(q, pos, neg, qb8, nb8, out);
    iw_main <<<dim3(NQ / 128, SPLIT), 256, 0, stream>>>(qb8, nb8, partial);
    iw_merge<<<32,   256, 0, stream>>>(partial, out);
}